// Round 1
// baseline (57.429 us; speedup 1.0000x reference)
//
#include <hip/hip_runtime.h>
#include <hip/hip_bf16.h>
#include <math.h>

#define N_EV_MAX 4096
#define N_SP 64

// ---------------------------------------------------------------------------
// Kernel 1: per-event intensity -> log(relu(mu + val)) written to ws_logs[i]
// One wave (64 lanes) per event; 4 waves (4 events) per 256-thread block.
// Events + spaces + alpha staged in LDS (shared across the block's 4 waves).
// ---------------------------------------------------------------------------
__global__ __launch_bounds__(256) void hawkes_term1_kernel(
    const float* __restrict__ data,   // (n,2) interleaved t,s
    const float* __restrict__ mu,     // (64,)
    const float* __restrict__ alpha,  // (64,64) row-major
    const float* __restrict__ beta_p, // scalar
    float* __restrict__ ws_logs,      // (n,)
    int n)
{
    __shared__ float t_s[N_EV_MAX];
    __shared__ short s_s[N_EV_MAX];
    __shared__ float a_s[N_SP * N_SP];

    const int tid = threadIdx.x;

    for (int i = tid; i < n; i += 256) {
        t_s[i] = data[2 * i];
        s_s[i] = (short)data[2 * i + 1];
    }
    for (int i = tid; i < N_SP * N_SP; i += 256) a_s[i] = alpha[i];
    __syncthreads();

    const float beta = beta_p[0];
    const int wave = tid >> 6;
    const int lane = tid & 63;
    const int i = blockIdx.x * 4 + wave;
    if (i >= n) return;

    const float t_i = t_s[i];
    const int   s_i = (int)s_s[i];
    const float* __restrict__ arow = &a_s[s_i * N_SP];

    float acc = 0.0f;
    for (int j = lane; j < i; j += 64) {
        const float t_j = t_s[j];
        if (t_j != 0.0f) {
            // exp(-beta*(t_i - t_j)) = exp(beta*(t_j - t_i)); t_j <= t_i so arg <= 0
            acc = fmaf(arow[(int)s_s[j]], __expf(beta * (t_j - t_i)), acc);
        }
    }
    // wave-wide reduce (64 lanes)
    #pragma unroll
    for (int off = 32; off; off >>= 1) acc += __shfl_xor(acc, off, 64);

    if (lane == 0) {
        const float lam = fmaxf(mu[s_i] + beta * acc, 0.0f);
        ws_logs[i] = __logf(lam);  // lam==0 -> -inf, matching log(relu(x))
    }
}

// ---------------------------------------------------------------------------
// Kernel 2: integral term. One block per grid point g (100 blocks, 1024 thr).
// val_gs[g,s] = sum_n alpha[s, s_n] * beta * exp(beta*(t_n - t_g)) [t_n < t_g]
// lane = s; alpha stored transposed in LDS with stride 65 (bank-conflict-free
// gather alphaT[s_n*65 + lane]). 16 waves split the event range; deterministic
// LDS tree combine; block writes partial_g = sum_s relu(mu_s + val) to ws_g.
// ---------------------------------------------------------------------------
__global__ __launch_bounds__(1024) void hawkes_term2_kernel(
    const float* __restrict__ data,
    const float* __restrict__ mu,
    const float* __restrict__ alpha,
    const float* __restrict__ beta_p,
    float* __restrict__ ws_g,   // (INT_RES,)
    int n, float grid_step)
{
    __shared__ float t_s[N_EV_MAX];
    __shared__ short s_s[N_EV_MAX];
    __shared__ float at_s[N_SP * 65];   // transposed alpha, padded stride
    __shared__ float part[16 * N_SP];

    const int tid = threadIdx.x;

    for (int i = tid; i < n; i += 1024) {
        t_s[i] = data[2 * i];
        s_s[i] = (short)data[2 * i + 1];
    }
    for (int i = tid; i < N_SP * N_SP; i += 1024) {
        const int r = i >> 6;   // row s of alpha
        const int c = i & 63;   // col s_n
        at_s[c * 65 + r] = alpha[i];
    }
    __syncthreads();

    const float beta = beta_p[0];
    const int wave = tid >> 6;
    const int lane = tid & 63;  // = s
    const float t_g = (float)blockIdx.x * grid_step;

    float acc = 0.0f;
    const int chunk = (n + 15) / 16;
    const int start = wave * chunk;
    const int end   = min(start + chunk, n);
    for (int nn = start; nn < end; ++nn) {
        const float t_n = t_s[nn];
        if (t_n < t_g && t_n != 0.0f) {      // wave-uniform branch
            const float e = __expf(beta * (t_n - t_g));
            acc = fmaf(at_s[(int)s_s[nn] * 65 + lane], e, acc);
        }
    }
    part[wave * N_SP + lane] = acc;
    __syncthreads();

    if (tid < N_SP) {
        float v = 0.0f;
        #pragma unroll
        for (int w = 0; w < 16; ++w) v += part[w * N_SP + tid];
        float lam = fmaxf(mu[tid] + beta * v, 0.0f);
        #pragma unroll
        for (int off = 32; off; off >>= 1) lam += __shfl_xor(lam, off, 64);
        if (tid == 0) ws_g[blockIdx.x] = lam;
    }
}

// ---------------------------------------------------------------------------
// Kernel 3: final deterministic reduction -> out[0]
// ---------------------------------------------------------------------------
__global__ __launch_bounds__(256) void hawkes_final_kernel(
    const float* __restrict__ ws_logs,
    const float* __restrict__ ws_g,
    float* __restrict__ out,
    int n, int ng, float scale)
{
    __shared__ float red[256];
    const int tid = threadIdx.x;

    float s1 = 0.0f;
    for (int i = tid; i < n; i += 256) s1 += ws_logs[i];
    float s2 = 0.0f;
    for (int i = tid; i < ng; i += 256) s2 += ws_g[i];

    red[tid] = s1 - scale * s2;
    __syncthreads();
    #pragma unroll
    for (int off = 128; off; off >>= 1) {
        if (tid < off) red[tid] += red[tid + off];
        __syncthreads();
    }
    if (tid == 0) out[0] = red[0];
}

extern "C" void kernel_launch(void* const* d_in, const int* in_sizes, int n_in,
                              void* d_out, int out_size, void* d_ws, size_t ws_size,
                              hipStream_t stream) {
    const float* data  = (const float*)d_in[0];   // (n,2)
    const float* mu    = (const float*)d_in[1];   // (64,)
    const float* alpha = (const float*)d_in[2];   // (64,64)
    const float* beta  = (const float*)d_in[3];   // scalar
    float* out = (float*)d_out;

    const int n = in_sizes[0] / 2;                // 4096
    const int INT_RES = 100;
    const float T1 = 100.0f;
    const float grid_step = T1 / (float)(INT_RES - 1);  // linspace(0,T1,100) spacing
    const float scale = T1 / (float)INT_RES;

    float* ws_logs = (float*)d_ws;                // n floats
    float* ws_g    = ws_logs + N_EV_MAX;          // INT_RES floats

    const int blocks1 = (n + 3) / 4;
    hawkes_term1_kernel<<<blocks1, 256, 0, stream>>>(data, mu, alpha, beta, ws_logs, n);
    hawkes_term2_kernel<<<INT_RES, 1024, 0, stream>>>(data, mu, alpha, beta, ws_g, n, grid_step);
    hawkes_final_kernel<<<1, 256, 0, stream>>>(ws_logs, ws_g, out, n, INT_RES, scale);
}